// Round 12
// baseline (145.625 us; speedup 1.0000x reference)
//
#include <hip/hip_runtime.h>

// Problem dims (fixed by setup_inputs)
constexpr int Bb = 4, Cc = 128, Nn = 4096, Kk = 32, Ns = 16384;
constexpr int ROWS = Bb * Nn;   // 16384 (b*n) rows
constexpr int NK = Nn * Kk;     // 131072 floats per channel slab
constexpr float EPS = 1e-5f;

// ---- workspace layout (bytes) ----
constexpr size_t SZ_SEG   = (size_t)Bb * Ns * Cc * 4;   // 32 MB scatter-max targets
constexpr size_t OFF_SEG  = 0;
constexpr size_t SZ_GX    = (size_t)ROWS * Cc * 4;      // 8 MB
constexpr size_t OFF_GX   = OFF_SEG + SZ_SEG;
constexpr size_t OFF_H1   = OFF_GX + SZ_GX;
constexpr size_t OFF_H2   = OFF_H1 + SZ_GX;
constexpr size_t SZ_PART  = (size_t)256 * 128 * 2 * 4;  // 256 KB per stats-partial set
constexpr size_t OFF_P1   = OFF_H2 + SZ_GX;
constexpr size_t OFF_P2   = OFF_P1 + SZ_PART;
constexpr size_t OFF_FLAG = OFF_P2 + SZ_PART;           // 256 KB int32 verified flags

// ---- prep: zero gathered seg rows + write verified flags (no clearing needed) ----
// flags[bb*Ns+fi] = i (claiming gather-row). Garbage entry j validates only if
// fps[j]==fi with j in batch bb -- which itself proves fi is in the set.
__global__ __launch_bounds__(256) void k_prep(const int* __restrict__ fps,
                                              float4* __restrict__ seg4,
                                              int* __restrict__ flags) {
    int i = blockIdx.x * 8 + (threadIdx.x >> 5);    // gather-row index 0..16383
    int lane = threadIdx.x & 31;
    int bb = i >> 12;
    int fi = fps[i];
    if (lane == 0) flags[bb * Ns + fi] = i;
    seg4[((size_t)bb * Ns + fi) * 32 + lane] = float4{0.f, 0.f, 0.f, 0.f};
}

// ---- fused: local max over k + row-contiguous filtered atomic scatter ----
// grid (4096, 4), 256 threads. Block = one (b, n): 128 channels x 32 k.
// Phase 1: coalesced x loads, 3-shuffle max, park tile in LDS [ch][33].
// Phase 2: compacted flagged-k list (~7 of 32); per k, 128 consecutive lanes
//          sweep one seg row (256B-contiguous atomic runs per wave -- R10/R11
//          showed line-packing is the atomic cost driver, -27us). NEW (R12):
//          read-before-atomic on the L2-hot row. Rows are zero-init'd and
//          monotone-growing, so stale-read <= truth => skip-if-not-greater is
//          exact; curf>=0 subsumes the v>0 check. ~7.4M -> ~2.5M lane atomics.
__global__ __launch_bounds__(256) void k_scatter(
        const float* __restrict__ x, const int* __restrict__ gidx,
        const int* __restrict__ flags, const int* __restrict__ fps,
        float* __restrict__ gx, unsigned int* __restrict__ seg) {
    int nn = blockIdx.x, bb = blockIdx.y;
    int t = threadIdx.x;
    __shared__ float tile[128][33];
    __shared__ float gbuf[128];
    __shared__ unsigned int srow[32];
    __shared__ int klist[32];
    __shared__ int nflag;

    if (t == 0) nflag = 0;
    __syncthreads();
    if (t < 32) {
        int idxv = gidx[((bb * Nn + nn) << 5) + t];
        srow[t] = (unsigned int)(bb * Ns + idxv) * 128u;
        int fl = flags[bb * Ns + idxv];
        int j = fl & 16383;
        if (((j >> 12) == bb) && (fps[j] == idxv)) {
            int pos = atomicAdd(&nflag, 1);
            klist[pos] = t;
        }
    }

    int k4 = (t & 7) * 4;
    int cq = t >> 3;                    // 0..31
    const float* xb = x + (size_t)bb * Cc * NK + (size_t)nn * Kk;
    float4 v[4];
    #pragma unroll
    for (int p = 0; p < 4; p++)
        v[p] = *(const float4*)(xb + (size_t)(cq + p * 32) * NK + k4);

    #pragma unroll
    for (int p = 0; p < 4; p++) {
        int ch = cq + p * 32;
        float4 w = v[p];
        float m = fmaxf(fmaxf(w.x, w.y), fmaxf(w.z, w.w));
        m = fmaxf(m, __shfl_xor(m, 1, 64));
        m = fmaxf(m, __shfl_xor(m, 2, 64));
        m = fmaxf(m, __shfl_xor(m, 4, 64));
        if ((t & 7) == 0) gbuf[ch] = m;
        tile[ch][k4 + 0] = w.x; tile[ch][k4 + 1] = w.y;
        tile[ch][k4 + 2] = w.z; tile[ch][k4 + 3] = w.w;
    }
    __syncthreads();

    int nf = nflag;
    int ch = t & 127, rep = t >> 7;     // two half-blocks process 2 k's/iter
    for (int it = rep; it < nf; it += 2) {
        int k = klist[it];
        float val = tile[ch][k];
        unsigned int dst = srow[k] + ch;
        float curf = __uint_as_float(seg[dst]);     // monotone, >= 0
        if (val > curf) atomicMax(seg + dst, __float_as_uint(val));
    }
    if (t < 128) gx[((size_t)(bb * Nn + nn)) * 128 + t] = gbuf[t];
}

// ---- GEMM1: h1(row,128) = A(row,256) @ w1^T + b1 ; per-block BN partials ----
// 512 threads (8 waves), 64x128 tile, grid 256.
__global__ __launch_bounds__(512) void k_gemm1(
        const float* __restrict__ gx, const float* __restrict__ segf,
        const int* __restrict__ fps, const float* __restrict__ w1,
        const float* __restrict__ b1, float* __restrict__ h1,
        float* __restrict__ part) {
    __shared__ float As[32][68];    // [kc][row]
    __shared__ float Bs[32][132];   // [kc][col]
    __shared__ int rowbase[64];
    int t = threadIdx.x;
    int m0 = blockIdx.x * 64;
    if (t < 64) {
        int row = m0 + t;
        rowbase[t] = ((row >> 12) * Ns + fps[row]) * 128;
    }
    int tn = t & 31;    // cols tn*4..+3
    int tm = t >> 5;    // 0..15, rows tm*4..+3
    float acc[4][4] = {};
    for (int k0 = 0; k0 < 256; k0 += 32) {
        __syncthreads();
        {                                       // A: 2048 floats, 1 float4/thread
            int row = t >> 3;
            int c4 = (t & 7) * 4;
            int k = k0 + c4;
            float4 v;
            if (k0 < 128) v = *(const float4*)(gx + (size_t)(m0 + row) * 128 + k);
            else          v = *(const float4*)(segf + rowbase[row] + (k - 128));
            As[c4 + 0][row] = v.x; As[c4 + 1][row] = v.y;
            As[c4 + 2][row] = v.z; As[c4 + 3][row] = v.w;
        }
        #pragma unroll
        for (int i = 0; i < 2; i++) {           // B: 4096 floats
            int fq = t + i * 512;
            int col = fq >> 3;
            int c4 = (fq & 7) * 4;
            float4 v = *(const float4*)(w1 + (size_t)col * 256 + k0 + c4);
            Bs[c4 + 0][col] = v.x; Bs[c4 + 1][col] = v.y;
            Bs[c4 + 2][col] = v.z; Bs[c4 + 3][col] = v.w;
        }
        __syncthreads();
        #pragma unroll
        for (int kc = 0; kc < 32; kc++) {
            float4 a = *(const float4*)&As[kc][tm * 4];
            float4 bv = *(const float4*)&Bs[kc][tn * 4];
            float av[4] = {a.x, a.y, a.z, a.w};
            float bw[4] = {bv.x, bv.y, bv.z, bv.w};
            #pragma unroll
            for (int r = 0; r < 4; r++)
                #pragma unroll
                for (int c = 0; c < 4; c++) acc[r][c] += av[r] * bw[c];
        }
    }
    float4 bv = *(const float4*)(b1 + tn * 4);
    float s_[4] = {}, q_[4] = {};
    #pragma unroll
    for (int r = 0; r < 4; r++) {
        int row = m0 + tm * 4 + r;
        float o0 = acc[r][0] + bv.x, o1 = acc[r][1] + bv.y;
        float o2 = acc[r][2] + bv.z, o3 = acc[r][3] + bv.w;
        float4 o{o0, o1, o2, o3};
        *(float4*)(h1 + (size_t)row * 128 + tn * 4) = o;
        s_[0] += o0; s_[1] += o1; s_[2] += o2; s_[3] += o3;
        q_[0] += o0 * o0; q_[1] += o1 * o1; q_[2] += o2 * o2; q_[3] += o3 * o3;
    }
    __syncthreads();
    float* reds = &As[0][0];    // 2176 >= 16*128
    float* redq = &Bs[0][0];    // 4224 >= 16*128
    #pragma unroll
    for (int c = 0; c < 4; c++) {
        reds[tm * 128 + tn * 4 + c] = s_[c];
        redq[tm * 128 + tn * 4 + c] = q_[c];
    }
    __syncthreads();
    if (t < 128) {
        float s = 0.f, q = 0.f;
        #pragma unroll
        for (int j = 0; j < 16; j++) { s += reds[j * 128 + t]; q += redq[j * 128 + t]; }
        part[blockIdx.x * 128 + t] = s;
        part[32768 + blockIdx.x * 128 + t] = q;
    }
}

// ---- GEMM2: inline BN1 finalize, h2 = relu(bn1(h1)) @ w2^T + b2 ; BN2 partials ----
__global__ __launch_bounds__(512) void k_gemm2(
        const float* __restrict__ h1, const float* __restrict__ part1,
        const float* __restrict__ g1, const float* __restrict__ be1,
        const float* __restrict__ w2, const float* __restrict__ b2,
        float* __restrict__ h2, float* __restrict__ part2) {
    __shared__ float As[32][68];
    __shared__ float Bs[32][132];
    __shared__ float ssc[128], ssh[128], tmp[256];
    int t = threadIdx.x;
    int m0 = blockIdx.x * 64;
    if (t < 256) {          // inline finalize of BN1 stats
        int ch = t & 127;
        const float* src = part1 + (t >> 7) * 32768 + ch;
        float a = 0.f;
        #pragma unroll 8
        for (int j = 0; j < 256; j++) a += src[j * 128];
        tmp[t] = a;
    }
    __syncthreads();
    if (t < 128) {
        float mean = tmp[t] * (1.0f / 16384.0f);
        float var = tmp[t + 128] * (1.0f / 16384.0f) - mean * mean;
        float sc = g1[t] * rsqrtf(var + EPS);
        ssc[t] = sc;
        ssh[t] = be1[t] - mean * sc;
    }
    int tn = t & 31, tm = t >> 5;
    float acc[4][4] = {};
    for (int k0 = 0; k0 < 128; k0 += 32) {
        __syncthreads();
        {
            int row = t >> 3;
            int c4 = (t & 7) * 4;
            int k = k0 + c4;
            float4 v = *(const float4*)(h1 + (size_t)(m0 + row) * 128 + k);
            As[c4 + 0][row] = fmaxf(0.f, fmaf(v.x, ssc[k + 0], ssh[k + 0]));
            As[c4 + 1][row] = fmaxf(0.f, fmaf(v.y, ssc[k + 1], ssh[k + 1]));
            As[c4 + 2][row] = fmaxf(0.f, fmaf(v.z, ssc[k + 2], ssh[k + 2]));
            As[c4 + 3][row] = fmaxf(0.f, fmaf(v.w, ssc[k + 3], ssh[k + 3]));
        }
        #pragma unroll
        for (int i = 0; i < 2; i++) {
            int fq = t + i * 512;
            int col = fq >> 3;
            int c4 = (fq & 7) * 4;
            float4 v = *(const float4*)(w2 + (size_t)col * 128 + k0 + c4);
            Bs[c4 + 0][col] = v.x; Bs[c4 + 1][col] = v.y;
            Bs[c4 + 2][col] = v.z; Bs[c4 + 3][col] = v.w;
        }
        __syncthreads();
        #pragma unroll
        for (int kc = 0; kc < 32; kc++) {
            float4 a = *(const float4*)&As[kc][tm * 4];
            float4 bv = *(const float4*)&Bs[kc][tn * 4];
            float av[4] = {a.x, a.y, a.z, a.w};
            float bw[4] = {bv.x, bv.y, bv.z, bv.w};
            #pragma unroll
            for (int r = 0; r < 4; r++)
                #pragma unroll
                for (int c = 0; c < 4; c++) acc[r][c] += av[r] * bw[c];
        }
    }
    float4 bv = *(const float4*)(b2 + tn * 4);
    float s_[4] = {}, q_[4] = {};
    #pragma unroll
    for (int r = 0; r < 4; r++) {
        int row = m0 + tm * 4 + r;
        float o0 = acc[r][0] + bv.x, o1 = acc[r][1] + bv.y;
        float o2 = acc[r][2] + bv.z, o3 = acc[r][3] + bv.w;
        float4 o{o0, o1, o2, o3};
        *(float4*)(h2 + (size_t)row * 128 + tn * 4) = o;
        s_[0] += o0; s_[1] += o1; s_[2] += o2; s_[3] += o3;
        q_[0] += o0 * o0; q_[1] += o1 * o1; q_[2] += o2 * o2; q_[3] += o3 * o3;
    }
    __syncthreads();
    float* reds = &As[0][0];
    float* redq = &Bs[0][0];
    #pragma unroll
    for (int c = 0; c < 4; c++) {
        reds[tm * 128 + tn * 4 + c] = s_[c];
        redq[tm * 128 + tn * 4 + c] = q_[c];
    }
    __syncthreads();
    if (t < 128) {
        float s = 0.f, q = 0.f;
        #pragma unroll
        for (int j = 0; j < 16; j++) { s += reds[j * 128 + t]; q += redq[j * 128 + t]; }
        part2[blockIdx.x * 128 + t] = s;
        part2[32768 + blockIdx.x * 128 + t] = q;
    }
}

// ---- final: inline BN2 finalize, bn2+relu on h2, transpose to (b, c, n) ----
__global__ __launch_bounds__(512) void k_out(const float* __restrict__ h2,
                                             const float* __restrict__ part2,
                                             const float* __restrict__ g2,
                                             const float* __restrict__ be2,
                                             float* __restrict__ out) {
    __shared__ float tile[64][129];
    __shared__ float lsc[128], lsh[128], tmp[256];
    int t = threadIdx.x;
    int bb = blockIdx.y, n0 = blockIdx.x * 64;
    if (t < 256) {
        int ch = t & 127;
        const float* src = part2 + (t >> 7) * 32768 + ch;
        float a = 0.f;
        #pragma unroll 8
        for (int j = 0; j < 256; j++) a += src[j * 128];
        tmp[t] = a;
    }
    __syncthreads();
    if (t < 128) {
        float mean = tmp[t] * (1.0f / 16384.0f);
        float var = tmp[t + 128] * (1.0f / 16384.0f) - mean * mean;
        float sc = g2[t] * rsqrtf(var + EPS);
        lsc[t] = sc;
        lsh[t] = be2[t] - mean * sc;
    }
    #pragma unroll
    for (int i = 0; i < 4; i++) {               // load 64 rows x 128 ch
        int fq = t + i * 512;
        int row = fq >> 5;
        int c4 = (fq & 31) * 4;
        float4 v = *(const float4*)(h2 + ((size_t)(bb * Nn + n0 + row)) * 128 + c4);
        tile[row][c4 + 0] = v.x; tile[row][c4 + 1] = v.y;
        tile[row][c4 + 2] = v.z; tile[row][c4 + 3] = v.w;
    }
    __syncthreads();
    int j = t & 63, og = t >> 6;                // lanes sweep n for coalesced writes
    #pragma unroll
    for (int o = og; o < 128; o += 8) {
        float v = fmaxf(0.f, fmaf(tile[j][o], lsc[o], lsh[o]));
        out[((size_t)(bb * 128 + o)) * Nn + n0 + j] = v;
    }
}

extern "C" void kernel_launch(void* const* d_in, const int* in_sizes, int n_in,
                              void* d_out, int out_size, void* d_ws, size_t ws_size,
                              hipStream_t stream) {
    const float* x    = (const float*)d_in[0];
    const int*   gidx = (const int*)d_in[1];
    const int*   fps  = (const int*)d_in[2];
    // d_in[3] = N (16384), known statically
    const float* w1   = (const float*)d_in[4];
    const float* b1   = (const float*)d_in[5];
    const float* g1   = (const float*)d_in[6];
    const float* be1  = (const float*)d_in[7];
    const float* w2   = (const float*)d_in[8];
    const float* b2   = (const float*)d_in[9];
    const float* g2   = (const float*)d_in[10];
    const float* be2  = (const float*)d_in[11];
    float* out = (float*)d_out;

    char* ws = (char*)d_ws;
    unsigned int* seg  = (unsigned int*)(ws + OFF_SEG);
    float* segf        = (float*)(ws + OFF_SEG);
    float4* seg4       = (float4*)(ws + OFF_SEG);
    float* gx          = (float*)(ws + OFF_GX);
    float* h1          = (float*)(ws + OFF_H1);
    float* h2          = (float*)(ws + OFF_H2);
    float* part1       = (float*)(ws + OFF_P1);
    float* part2       = (float*)(ws + OFF_P2);
    int* flags         = (int*)(ws + OFF_FLAG);

    k_prep<<<ROWS / 8, 256, 0, stream>>>(fps, seg4, flags);
    k_scatter<<<dim3(Nn, Bb), 256, 0, stream>>>(x, gidx, flags, fps, gx, seg);
    k_gemm1<<<ROWS / 64, 512, 0, stream>>>(gx, segf, fps, w1, b1, h1, part1);
    k_gemm2<<<ROWS / 64, 512, 0, stream>>>(h1, part1, g1, be1, w2, b2, h2, part2);
    k_out<<<dim3(Nn / 64, Bb), 512, 0, stream>>>(h2, part2, g2, be2, out);
}

// Round 13
// 124.871 us; speedup vs baseline: 1.1662x; 1.1662x over previous
//
#include <hip/hip_runtime.h>

// Problem dims (fixed by setup_inputs)
constexpr int Bb = 4, Cc = 128, Nn = 4096, Kk = 32, Ns = 16384;
constexpr int ROWS = Bb * Nn;   // 16384 (b*n) rows
constexpr int NK = Nn * Kk;     // 131072 floats per channel slab
constexpr float EPS = 1e-5f;

typedef __attribute__((ext_vector_type(8))) short short8;
typedef __attribute__((ext_vector_type(4))) float f32x4;

__device__ __forceinline__ unsigned short f2bf(float f) {   // RNE f32->bf16
    unsigned int u = __float_as_uint(f);
    unsigned int r = u + 0x7FFFu + ((u >> 16) & 1u);
    return (unsigned short)(r >> 16);
}

// ---- workspace layout (bytes) ----
constexpr size_t SZ_SEG   = (size_t)Bb * Ns * Cc * 4;   // 32 MB scatter-max targets
constexpr size_t OFF_SEG  = 0;
constexpr size_t SZ_GX    = (size_t)ROWS * Cc * 4;      // 8 MB
constexpr size_t OFF_GX   = OFF_SEG + SZ_SEG;
constexpr size_t OFF_H1   = OFF_GX + SZ_GX;
constexpr size_t OFF_H2   = OFF_H1 + SZ_GX;
constexpr size_t SZ_PART  = (size_t)256 * 128 * 2 * 4;  // 256 KB per stats-partial set
constexpr size_t OFF_P1   = OFF_H2 + SZ_GX;
constexpr size_t OFF_P2   = OFF_P1 + SZ_PART;
constexpr size_t OFF_FLAG = OFF_P2 + SZ_PART;           // 256 KB int32 verified flags

// ---- prep: zero gathered seg rows + write verified flags (no clearing needed) ----
__global__ __launch_bounds__(256) void k_prep(const int* __restrict__ fps,
                                              float4* __restrict__ seg4,
                                              int* __restrict__ flags) {
    int i = blockIdx.x * 8 + (threadIdx.x >> 5);    // gather-row index 0..16383
    int lane = threadIdx.x & 31;
    int bb = i >> 12;
    int fi = fps[i];
    if (lane == 0) flags[bb * Ns + fi] = i;
    seg4[((size_t)bb * Ns + fi) * 32 + lane] = float4{0.f, 0.f, 0.f, 0.f};
}

// ---- fused: local max over k + row-contiguous atomic scatter (R11 form) ----
__global__ __launch_bounds__(256) void k_scatter(
        const float* __restrict__ x, const int* __restrict__ gidx,
        const int* __restrict__ flags, const int* __restrict__ fps,
        float* __restrict__ gx, unsigned int* __restrict__ seg) {
    int nn = blockIdx.x, bb = blockIdx.y;
    int t = threadIdx.x;
    __shared__ float tile[128][33];
    __shared__ float gbuf[128];
    __shared__ unsigned int srow[32];
    __shared__ int klist[32];
    __shared__ int nflag;

    if (t == 0) nflag = 0;
    __syncthreads();
    if (t < 32) {
        int idxv = gidx[((bb * Nn + nn) << 5) + t];
        srow[t] = (unsigned int)(bb * Ns + idxv) * 128u;
        int fl = flags[bb * Ns + idxv];
        int j = fl & 16383;
        if (((j >> 12) == bb) && (fps[j] == idxv)) {
            int pos = atomicAdd(&nflag, 1);
            klist[pos] = t;
        }
    }

    int k4 = (t & 7) * 4;
    int cq = t >> 3;                    // 0..31
    const float* xb = x + (size_t)bb * Cc * NK + (size_t)nn * Kk;
    float4 v[4];
    #pragma unroll
    for (int p = 0; p < 4; p++)
        v[p] = *(const float4*)(xb + (size_t)(cq + p * 32) * NK + k4);

    #pragma unroll
    for (int p = 0; p < 4; p++) {
        int ch = cq + p * 32;
        float4 w = v[p];
        float m = fmaxf(fmaxf(w.x, w.y), fmaxf(w.z, w.w));
        m = fmaxf(m, __shfl_xor(m, 1, 64));
        m = fmaxf(m, __shfl_xor(m, 2, 64));
        m = fmaxf(m, __shfl_xor(m, 4, 64));
        if ((t & 7) == 0) gbuf[ch] = m;
        tile[ch][k4 + 0] = w.x; tile[ch][k4 + 1] = w.y;
        tile[ch][k4 + 2] = w.z; tile[ch][k4 + 3] = w.w;
    }
    __syncthreads();

    int nf = nflag;
    int ch = t & 127, rep = t >> 7;     // two half-blocks process 2 k's/iter
    for (int it = rep; it < nf; it += 2) {
        int k = klist[it];
        float val = tile[ch][k];
        if (val > 0.f) atomicMax(seg + srow[k] + ch, __float_as_uint(val));
    }
    if (t < 128) gx[((size_t)(bb * Nn + nn)) * 128 + t] = gbuf[t];
}

// ---- GEMM1 (bf16 MFMA): h1(row,128) = A(row,256) @ w1^T + b1 ; BN partials ----
// 512 thr = 8 waves; wave w: rows r0=(w>>1)*16, cols c0=(w&1)*64 (4x 16x16 frags).
// K staged in 64-steps to LDS as bf16 [row][72] (pad 8 -> <=2-way conflicts).
// Fragment layout: A row=l&15, k=(l>>4)*8+e ; B col=l&15, same k ; D col=l&15,
// row=(l>>4)*4+reg (guide-verified). f32 accumulate keeps h1 near-exact.
__global__ __launch_bounds__(512) void k_gemm1(
        const float* __restrict__ gx, const float* __restrict__ segf,
        const int* __restrict__ fps, const float* __restrict__ w1,
        const float* __restrict__ b1, float* __restrict__ h1,
        float* __restrict__ part) {
    __shared__ __align__(16) unsigned short A_lds[64][72];
    __shared__ __align__(16) unsigned short B_lds[128][72];
    __shared__ float reds[4][128], redq[4][128];
    __shared__ int rowbase[64];
    int t = threadIdx.x;
    int m0 = blockIdx.x * 64;
    if (t < 64) rowbase[t] = (((m0 + t) >> 12) * Ns + fps[m0 + t]) * 128;
    int w = t >> 6, l = t & 63;
    int r0 = (w >> 1) * 16, c0 = (w & 1) * 64;
    int lr = l & 15, lk = (l >> 4) * 8;
    f32x4 acc[4] = {};
    for (int k0 = 0; k0 < 256; k0 += 64) {
        __syncthreads();
        #pragma unroll
        for (int i = 0; i < 2; i++) {           // A: 64x64 f32 -> bf16
            int q = t + i * 512;
            int row = q >> 4, kq = (q & 15) * 4;
            int k = k0 + kq;
            float4 v;
            if (k0 < 128) v = *(const float4*)(gx + (size_t)(m0 + row) * 128 + k);
            else          v = *(const float4*)(segf + rowbase[row] + (k - 128));
            ushort4 o{f2bf(v.x), f2bf(v.y), f2bf(v.z), f2bf(v.w)};
            *(ushort4*)&A_lds[row][kq] = o;
        }
        #pragma unroll
        for (int i = 0; i < 4; i++) {           // B: 128x64 from w1[col][k]
            int q = t + i * 512;
            int col = q >> 4, kq = (q & 15) * 4;
            float4 v = *(const float4*)(w1 + (size_t)col * 256 + k0 + kq);
            ushort4 o{f2bf(v.x), f2bf(v.y), f2bf(v.z), f2bf(v.w)};
            *(ushort4*)&B_lds[col][kq] = o;
        }
        __syncthreads();
        #pragma unroll
        for (int ks = 0; ks < 2; ks++) {
            short8 a = *(const short8*)&A_lds[r0 + lr][ks * 32 + lk];
            #pragma unroll
            for (int cb = 0; cb < 4; cb++) {
                short8 b = *(const short8*)&B_lds[c0 + cb * 16 + lr][ks * 32 + lk];
                acc[cb] = __builtin_amdgcn_mfma_f32_16x16x32_bf16(a, b, acc[cb], 0, 0, 0);
            }
        }
    }
    int orow = m0 + r0 + (l >> 4) * 4;
    #pragma unroll
    for (int cb = 0; cb < 4; cb++) {
        int col = c0 + cb * 16 + lr;
        float bias = b1[col];
        float sv = 0.f, qv = 0.f;
        #pragma unroll
        for (int r = 0; r < 4; r++) {
            float o = acc[cb][r] + bias;
            h1[(size_t)(orow + r) * 128 + col] = o;
            sv += o; qv += o * o;
        }
        sv += __shfl_xor(sv, 16, 64); sv += __shfl_xor(sv, 32, 64);
        qv += __shfl_xor(qv, 16, 64); qv += __shfl_xor(qv, 32, 64);
        if (l < 16) { reds[w >> 1][col] = sv; redq[w >> 1][col] = qv; }
    }
    __syncthreads();
    if (t < 128) {
        float s = reds[0][t] + reds[1][t] + reds[2][t] + reds[3][t];
        float q = redq[0][t] + redq[1][t] + redq[2][t] + redq[3][t];
        part[blockIdx.x * 128 + t] = s;
        part[32768 + blockIdx.x * 128 + t] = q;
    }
}

// ---- GEMM2 (bf16 MFMA): inline BN1 finalize, h2 = relu(bn1(h1)) @ w2^T + b2 ----
__global__ __launch_bounds__(512) void k_gemm2(
        const float* __restrict__ h1, const float* __restrict__ part1,
        const float* __restrict__ g1, const float* __restrict__ be1,
        const float* __restrict__ w2, const float* __restrict__ b2,
        float* __restrict__ h2, float* __restrict__ part2) {
    __shared__ __align__(16) unsigned short A_lds[64][72];
    __shared__ __align__(16) unsigned short B_lds[128][72];
    __shared__ float reds[4][128], redq[4][128];
    __shared__ float ssc[128], ssh[128], tmp[256];
    int t = threadIdx.x;
    int m0 = blockIdx.x * 64;
    if (t < 256) {          // inline finalize of BN1 stats
        int ch = t & 127;
        const float* src = part1 + (t >> 7) * 32768 + ch;
        float a = 0.f;
        #pragma unroll 8
        for (int j = 0; j < 256; j++) a += src[j * 128];
        tmp[t] = a;
    }
    __syncthreads();
    if (t < 128) {
        float mean = tmp[t] * (1.0f / 16384.0f);
        float var = tmp[t + 128] * (1.0f / 16384.0f) - mean * mean;
        float sc = g1[t] * rsqrtf(var + EPS);
        ssc[t] = sc;
        ssh[t] = be1[t] - mean * sc;
    }
    __syncthreads();
    int w = t >> 6, l = t & 63;
    int r0 = (w >> 1) * 16, c0 = (w & 1) * 64;
    int lr = l & 15, lk = (l >> 4) * 8;
    f32x4 acc[4] = {};
    for (int k0 = 0; k0 < 128; k0 += 64) {
        __syncthreads();
        #pragma unroll
        for (int i = 0; i < 2; i++) {           // A: relu(bn1(h1)) -> bf16
            int q = t + i * 512;
            int row = q >> 4, kq = (q & 15) * 4;
            int k = k0 + kq;
            float4 v = *(const float4*)(h1 + (size_t)(m0 + row) * 128 + k);
            float a0 = fmaxf(0.f, fmaf(v.x, ssc[k + 0], ssh[k + 0]));
            float a1 = fmaxf(0.f, fmaf(v.y, ssc[k + 1], ssh[k + 1]));
            float a2 = fmaxf(0.f, fmaf(v.z, ssc[k + 2], ssh[k + 2]));
            float a3 = fmaxf(0.f, fmaf(v.w, ssc[k + 3], ssh[k + 3]));
            ushort4 o{f2bf(a0), f2bf(a1), f2bf(a2), f2bf(a3)};
            *(ushort4*)&A_lds[row][kq] = o;
        }
        #pragma unroll
        for (int i = 0; i < 4; i++) {           // B: 128x64 from w2[col][k]
            int q = t + i * 512;
            int col = q >> 4, kq = (q & 15) * 4;
            float4 v = *(const float4*)(w2 + (size_t)col * 128 + k0 + kq);
            ushort4 o{f2bf(v.x), f2bf(v.y), f2bf(v.z), f2bf(v.w)};
            *(ushort4*)&B_lds[col][kq] = o;
        }
        __syncthreads();
        #pragma unroll
        for (int ks = 0; ks < 2; ks++) {
            short8 a = *(const short8*)&A_lds[r0 + lr][ks * 32 + lk];
            #pragma unroll
            for (int cb = 0; cb < 4; cb++) {
                short8 b = *(const short8*)&B_lds[c0 + cb * 16 + lr][ks * 32 + lk];
                acc[cb] = __builtin_amdgcn_mfma_f32_16x16x32_bf16(a, b, acc[cb], 0, 0, 0);
            }
        }
    }
    int orow = m0 + r0 + (l >> 4) * 4;
    #pragma unroll
    for (int cb = 0; cb < 4; cb++) {
        int col = c0 + cb * 16 + lr;
        float bias = b2[col];
        float sv = 0.f, qv = 0.f;
        #pragma unroll
        for (int r = 0; r < 4; r++) {
            float o = acc[cb][r] + bias;
            h2[(size_t)(orow + r) * 128 + col] = o;
            sv += o; qv += o * o;
        }
        sv += __shfl_xor(sv, 16, 64); sv += __shfl_xor(sv, 32, 64);
        qv += __shfl_xor(qv, 16, 64); qv += __shfl_xor(qv, 32, 64);
        if (l < 16) { reds[w >> 1][col] = sv; redq[w >> 1][col] = qv; }
    }
    __syncthreads();
    if (t < 128) {
        float s = reds[0][t] + reds[1][t] + reds[2][t] + reds[3][t];
        float q = redq[0][t] + redq[1][t] + redq[2][t] + redq[3][t];
        part2[blockIdx.x * 128 + t] = s;
        part2[32768 + blockIdx.x * 128 + t] = q;
    }
}

// ---- final: inline BN2 finalize, bn2+relu on h2, transpose to (b, c, n) ----
__global__ __launch_bounds__(512) void k_out(const float* __restrict__ h2,
                                             const float* __restrict__ part2,
                                             const float* __restrict__ g2,
                                             const float* __restrict__ be2,
                                             float* __restrict__ out) {
    __shared__ float tile[64][129];
    __shared__ float lsc[128], lsh[128], tmp[256];
    int t = threadIdx.x;
    int bb = blockIdx.y, n0 = blockIdx.x * 64;
    if (t < 256) {
        int ch = t & 127;
        const float* src = part2 + (t >> 7) * 32768 + ch;
        float a = 0.f;
        #pragma unroll 8
        for (int j = 0; j < 256; j++) a += src[j * 128];
        tmp[t] = a;
    }
    __syncthreads();
    if (t < 128) {
        float mean = tmp[t] * (1.0f / 16384.0f);
        float var = tmp[t + 128] * (1.0f / 16384.0f) - mean * mean;
        float sc = g2[t] * rsqrtf(var + EPS);
        lsc[t] = sc;
        lsh[t] = be2[t] - mean * sc;
    }
    #pragma unroll
    for (int i = 0; i < 4; i++) {               // load 64 rows x 128 ch
        int fq = t + i * 512;
        int row = fq >> 5;
        int c4 = (fq & 31) * 4;
        float4 v = *(const float4*)(h2 + ((size_t)(bb * Nn + n0 + row)) * 128 + c4);
        tile[row][c4 + 0] = v.x; tile[row][c4 + 1] = v.y;
        tile[row][c4 + 2] = v.z; tile[row][c4 + 3] = v.w;
    }
    __syncthreads();
    int j = t & 63, og = t >> 6;                // lanes sweep n for coalesced writes
    #pragma unroll
    for (int o = og; o < 128; o += 8) {
        float v = fmaxf(0.f, fmaf(tile[j][o], lsc[o], lsh[o]));
        out[((size_t)(bb * 128 + o)) * Nn + n0 + j] = v;
    }
}

extern "C" void kernel_launch(void* const* d_in, const int* in_sizes, int n_in,
                              void* d_out, int out_size, void* d_ws, size_t ws_size,
                              hipStream_t stream) {
    const float* x    = (const float*)d_in[0];
    const int*   gidx = (const int*)d_in[1];
    const int*   fps  = (const int*)d_in[2];
    // d_in[3] = N (16384), known statically
    const float* w1   = (const float*)d_in[4];
    const float* b1   = (const float*)d_in[5];
    const float* g1   = (const float*)d_in[6];
    const float* be1  = (const float*)d_in[7];
    const float* w2   = (const float*)d_in[8];
    const float* b2   = (const float*)d_in[9];
    const float* g2   = (const float*)d_in[10];
    const float* be2  = (const float*)d_in[11];
    float* out = (float*)d_out;

    char* ws = (char*)d_ws;
    unsigned int* seg  = (unsigned int*)(ws + OFF_SEG);
    float* segf        = (float*)(ws + OFF_SEG);
    float4* seg4       = (float4*)(ws + OFF_SEG);
    float* gx          = (float*)(ws + OFF_GX);
    float* h1          = (float*)(ws + OFF_H1);
    float* h2          = (float*)(ws + OFF_H2);
    float* part1       = (float*)(ws + OFF_P1);
    float* part2       = (float*)(ws + OFF_P2);
    int* flags         = (int*)(ws + OFF_FLAG);

    k_prep<<<ROWS / 8, 256, 0, stream>>>(fps, seg4, flags);
    k_scatter<<<dim3(Nn, Bb), 256, 0, stream>>>(x, gidx, flags, fps, gx, seg);
    k_gemm1<<<ROWS / 64, 512, 0, stream>>>(gx, segf, fps, w1, b1, h1, part1);
    k_gemm2<<<ROWS / 64, 512, 0, stream>>>(h1, part1, g1, be1, w2, b2, h2, part2);
    k_out<<<dim3(Nn / 64, Bb), 512, 0, stream>>>(h2, part2, g2, be2, out);
}